// Round 9
// baseline (97.886 us; speedup 1.0000x reference)
//
#include <hip/hip_runtime.h>
#include <math.h>

#define BB 4
#define NN 5
#define CC_DIM 64
#define HH 100
#define WW 252
#define HW (HH * WW)
#define CPT 4               // channels per thread (halved vs R8 to restore occupancy)
#define NCHUNK (CC_DIM / CPT)  // 16 chunks
#define HP (HH / 2)         // 50 row-pairs

__global__ __launch_bounds__(256) void where2comm_fuse_kernel(
    const float* __restrict__ x,    // (B*N, C, H, W)
    const float* __restrict__ ptm,  // (B, N, N, 2, 3)
    float* __restrict__ out)        // (B, C, H, W) + 1 scalar
{
    const int idx = blockIdx.x * blockDim.x + threadIdx.x;
    // total = BB * NCHUNK * HP * WW = 806400, grid exact

    // decompose: w fastest, then row-pair, then channel-chunk, then b
    int w = idx % WW;
    int t = idx / WW;
    int hp = t % HP;
    t /= HP;
    int cc = t % NCHUNK;
    int b = t / NCHUNK;

    const int h0 = 2 * hp;
    const int h1 = h0 + 1;

    const float gx = (2.0f * (float)w + 1.0f) / (float)WW - 1.0f;
    const float gy0 = (2.0f * (float)h0 + 1.0f) / (float)HH - 1.0f;
    const float gy1 = (2.0f * (float)h1 + 1.0f) / (float)HH - 1.0f;

    const float* th_b = ptm + (size_t)b * (NN * NN * 6);  // theta[b,0,n,:,:]

    float acc0[CPT], acc1[CPT];
#pragma unroll
    for (int c = 0; c < CPT; ++c) { acc0[c] = -INFINITY; acc1[c] = -INFINITY; }

#pragma unroll
    for (int n = 0; n < NN; ++n) {
        const float t00 = th_b[n * 6 + 0];
        const float t01 = th_b[n * 6 + 1];
        const float t02 = th_b[n * 6 + 2];
        const float t10 = th_b[n * 6 + 3];
        const float t11 = th_b[n * 6 + 4];
        const float t12 = th_b[n * 6 + 5];

        // ---- geometry for both output rows (reference formulas) ----
        int clA, rlA, clB, rlB;
        float gA00, gA01, gA10, gA11, gB00, gB01, gB10, gB11;

#define GEOM(GY, CL, RL, G00, G01, G10, G11)                                   \
        {                                                                      \
            const float cx = t00 * gx + t01 * (GY) + t02;                      \
            const float cy = t10 * gx + t11 * (GY) + t12;                      \
            const float ix = ((cx + 1.0f) * (float)WW - 1.0f) * 0.5f;          \
            const float iy = ((cy + 1.0f) * (float)HH - 1.0f) * 0.5f;          \
            const float x0f = floorf(ix);                                      \
            const float y0f = floorf(iy);                                      \
            const float x1f = x0f + 1.0f;                                      \
            const float y1f = y0f + 1.0f;                                      \
            const float wx1 = ix - x0f;                                        \
            const float wx0 = 1.0f - wx1;                                      \
            const float wy1 = iy - y0f;                                        \
            const float wy0 = 1.0f - wy1;                                      \
            const float mx0 = (x0f >= 0.0f && x0f <= (float)(WW - 1)) ? 1.0f : 0.0f; \
            const float mx1 = (x1f >= 0.0f && x1f <= (float)(WW - 1)) ? 1.0f : 0.0f; \
            const float my0 = (y0f >= 0.0f && y0f <= (float)(HH - 1)) ? 1.0f : 0.0f; \
            const float my1 = (y1f >= 0.0f && y1f <= (float)(HH - 1)) ? 1.0f : 0.0f; \
            const float e00 = wx0 * wy0 * mx0 * my0;                           \
            const float e10 = wx1 * wy0 * mx1 * my0;                           \
            const float e01 = wx0 * wy1 * mx0 * my1;                           \
            const float e11 = wx1 * wy1 * mx1 * my1;                           \
            const int xi0 = (int)fminf(fmaxf(x0f, 0.0f), (float)(WW - 1));     \
            const int xi1 = (int)fminf(fmaxf(x1f, 0.0f), (float)(WW - 1));     \
            const int yi0 = (int)fminf(fmaxf(y0f, 0.0f), (float)(HH - 1));     \
            const int yi1 = (int)fminf(fmaxf(y1f, 0.0f), (float)(HH - 1));     \
            CL = (int)fminf(fmaxf(x0f, 0.0f), (float)(WW - 2));                \
            RL = (int)fminf(fmaxf(y0f, 0.0f), (float)(HH - 2));                \
            const float sx0 = (float)(xi0 - CL);                               \
            const float sx1 = (float)(xi1 - CL);                               \
            const float sy0 = (float)(yi0 - RL);                               \
            const float sy1 = (float)(yi1 - RL);                               \
            const float nx0 = 1.0f - sx0, nx1 = 1.0f - sx1;                    \
            const float ny0 = 1.0f - sy0, ny1 = 1.0f - sy1;                    \
            G00 = e00 * nx0 * ny0 + e10 * nx1 * ny0 + e01 * nx0 * ny1 + e11 * nx1 * ny1; \
            G01 = e00 * sx0 * ny0 + e10 * sx1 * ny0 + e01 * sx0 * ny1 + e11 * sx1 * ny1; \
            G10 = e00 * nx0 * sy0 + e10 * nx1 * sy0 + e01 * nx0 * sy1 + e11 * nx1 * sy1; \
            G11 = e00 * sx0 * sy0 + e10 * sx1 * sy0 + e01 * sx0 * sy1 + e11 * sx1 * sy1; \
        }

        GEOM(gy0, clA, rlA, gA00, gA01, gA10, gA11)
        GEOM(gy1, clB, rlB, gB00, gB01, gB10, gB11)
#undef GEOM

        const float* plane = x + ((size_t)(b * NN + n) * CC_DIM + cc * CPT) * HW;
        const int offA = rlA * WW + clA;
        const int offB = rlB * WW + clB;

        // ---- load row-pair patch for h0 ----
        float L0[CPT][2], L1[CPT][2];
#pragma unroll
        for (int c = 0; c < CPT; ++c) {
            const float* pc = plane + (size_t)c * HW + offA;
            __builtin_memcpy(&L0[c][0], pc, 8);
            __builtin_memcpy(&L1[c][0], pc + WW, 8);
        }

        // ---- consume h0 ----
#pragma unroll
        for (int c = 0; c < CPT; ++c) {
            float v = L0[c][0] * gA00;
            v = fmaf(L0[c][1], gA01, v);
            v = fmaf(L1[c][0], gA10, v);
            v = fmaf(L1[c][1], gA11, v);
            acc0[c] = fmaxf(acc0[c], v);
        }

        // ---- select/load patch for h1, reusing registers when possible ----
        const bool sameCol = (clB == clA);
        const bool reuse0 = sameCol && (rlB == rlA);      // 0 new loads
        const bool reuse1 = sameCol && (rlB == rlA + 1);  // 1 new row

        float P[CPT][2], Q[CPT][2];
        if (reuse0) {
#pragma unroll
            for (int c = 0; c < CPT; ++c) {
                P[c][0] = L0[c][0]; P[c][1] = L0[c][1];
                Q[c][0] = L1[c][0]; Q[c][1] = L1[c][1];
            }
        } else if (reuse1) {
#pragma unroll
            for (int c = 0; c < CPT; ++c) {
                P[c][0] = L1[c][0]; P[c][1] = L1[c][1];
                __builtin_memcpy(&Q[c][0], plane + (size_t)c * HW + offB + WW, 8);
            }
        } else {
#pragma unroll
            for (int c = 0; c < CPT; ++c) {
                const float* pc = plane + (size_t)c * HW + offB;
                __builtin_memcpy(&P[c][0], pc, 8);
                __builtin_memcpy(&Q[c][0], pc + WW, 8);
            }
        }

        // ---- consume h1 ----
#pragma unroll
        for (int c = 0; c < CPT; ++c) {
            float v = P[c][0] * gB00;
            v = fmaf(P[c][1], gB01, v);
            v = fmaf(Q[c][0], gB10, v);
            v = fmaf(Q[c][1], gB11, v);
            acc1[c] = fmaxf(acc1[c], v);
        }
    }

    // ---- write outputs: out[b, cc*CPT + c, h0/h1, w] ----
#pragma unroll
    for (int c = 0; c < CPT; ++c) {
        const size_t rowbase = ((size_t)(b * CC_DIM + cc * CPT + c) * HH + h0) * WW + w;
        out[rowbase] = acc0[c];
        out[rowbase + WW] = acc1[c];
    }

    if (idx == 0) {
        out[(size_t)BB * CC_DIM * HW] = 0.0f;  // communication_rates
    }
}

extern "C" void kernel_launch(void* const* d_in, const int* in_sizes, int n_in,
                              void* d_out, int out_size, void* d_ws, size_t ws_size,
                              hipStream_t stream) {
    const float* x = (const float*)d_in[0];
    const float* ptm = (const float*)d_in[3];
    float* out = (float*)d_out;

    const int total = BB * NCHUNK * HP * WW;  // 806400
    const int block = 256;
    const int grid = total / block;           // 3150
    where2comm_fuse_kernel<<<grid, block, 0, stream>>>(x, ptm, out);
}

// Round 10
// 58.946 us; speedup vs baseline: 1.6606x; 1.6606x over previous
//
#include <hip/hip_runtime.h>
#include <math.h>

#define BB 4
#define NN 5
#define CC_DIM 64
#define HH 100
#define WW 252
#define HW (HH * WW)
#define CPT 8              // channels per thread (GEOM amortized over 8)
#define NCHUNK (CC_DIM / CPT)  // 8 chunks
#define HP (HH / 2)        // 50 row-pairs

__global__ __launch_bounds__(256, 4) void where2comm_fuse_kernel(
    const float* __restrict__ x,    // (B*N, C, H, W)
    const float* __restrict__ ptm,  // (B, N, N, 2, 3)
    float* __restrict__ out)        // (B, C, H, W) + 1 scalar
{
    const int idx = blockIdx.x * blockDim.x + threadIdx.x;
    // total = BB * NCHUNK * HP * WW = 403200, grid exact

    int w = idx % WW;
    int t = idx / WW;
    int hp = t % HP;
    t /= HP;
    int cc = t % NCHUNK;
    int b = t / NCHUNK;

    const int h0 = 2 * hp;
    const int h1 = h0 + 1;

    const float gx = (2.0f * (float)w + 1.0f) / (float)WW - 1.0f;
    const float gy0 = (2.0f * (float)h0 + 1.0f) / (float)HH - 1.0f;
    const float gy1 = (2.0f * (float)h1 + 1.0f) / (float)HH - 1.0f;

    const float* th_b = ptm + (size_t)b * (NN * NN * 6);  // theta[b,0,n,:,:]

    float acc0[CPT], acc1[CPT];
#pragma unroll
    for (int c = 0; c < CPT; ++c) { acc0[c] = -INFINITY; acc1[c] = -INFINITY; }

    // GEOM: computes patch origin (CL,RL) and routed weights for one output row.
#define GEOM(GY, CL, RL, G00, G01, G10, G11)                                   \
        {                                                                      \
            const float cx = t00 * gx + t01 * (GY) + t02;                      \
            const float cy = t10 * gx + t11 * (GY) + t12;                      \
            const float ix = ((cx + 1.0f) * (float)WW - 1.0f) * 0.5f;          \
            const float iy = ((cy + 1.0f) * (float)HH - 1.0f) * 0.5f;          \
            const float x0f = floorf(ix);                                      \
            const float y0f = floorf(iy);                                      \
            const float x1f = x0f + 1.0f;                                      \
            const float y1f = y0f + 1.0f;                                      \
            const float wx1 = ix - x0f;                                        \
            const float wx0 = 1.0f - wx1;                                      \
            const float wy1 = iy - y0f;                                        \
            const float wy0 = 1.0f - wy1;                                      \
            const float mx0 = (x0f >= 0.0f && x0f <= (float)(WW - 1)) ? 1.0f : 0.0f; \
            const float mx1 = (x1f >= 0.0f && x1f <= (float)(WW - 1)) ? 1.0f : 0.0f; \
            const float my0 = (y0f >= 0.0f && y0f <= (float)(HH - 1)) ? 1.0f : 0.0f; \
            const float my1 = (y1f >= 0.0f && y1f <= (float)(HH - 1)) ? 1.0f : 0.0f; \
            const float e00 = wx0 * wy0 * mx0 * my0;                           \
            const float e10 = wx1 * wy0 * mx1 * my0;                           \
            const float e01 = wx0 * wy1 * mx0 * my1;                           \
            const float e11 = wx1 * wy1 * mx1 * my1;                           \
            const int xi0 = (int)fminf(fmaxf(x0f, 0.0f), (float)(WW - 1));     \
            const int xi1 = (int)fminf(fmaxf(x1f, 0.0f), (float)(WW - 1));     \
            const int yi0 = (int)fminf(fmaxf(y0f, 0.0f), (float)(HH - 1));     \
            const int yi1 = (int)fminf(fmaxf(y1f, 0.0f), (float)(HH - 1));     \
            CL = (int)fminf(fmaxf(x0f, 0.0f), (float)(WW - 2));                \
            RL = (int)fminf(fmaxf(y0f, 0.0f), (float)(HH - 2));                \
            const float sx0 = (float)(xi0 - CL);                               \
            const float sx1 = (float)(xi1 - CL);                               \
            const float sy0 = (float)(yi0 - RL);                               \
            const float sy1 = (float)(yi1 - RL);                               \
            const float nx0 = 1.0f - sx0, nx1 = 1.0f - sx1;                    \
            const float ny0 = 1.0f - sy0, ny1 = 1.0f - sy1;                    \
            G00 = e00 * nx0 * ny0 + e10 * nx1 * ny0 + e01 * nx0 * ny1 + e11 * nx1 * ny1; \
            G01 = e00 * sx0 * ny0 + e10 * sx1 * ny0 + e01 * sx0 * ny1 + e11 * sx1 * ny1; \
            G10 = e00 * nx0 * sy0 + e10 * nx1 * sy0 + e01 * nx0 * sy1 + e11 * nx1 * sy1; \
            G11 = e00 * sx0 * sy0 + e10 * sx1 * sy0 + e01 * sx0 * sy1 + e11 * sx1 * sy1; \
        }

#pragma unroll 1
    for (int n = 0; n < NN; ++n) {
        const float t00 = th_b[n * 6 + 0];
        const float t01 = th_b[n * 6 + 1];
        const float t02 = th_b[n * 6 + 2];
        const float t10 = th_b[n * 6 + 3];
        const float t11 = th_b[n * 6 + 4];
        const float t12 = th_b[n * 6 + 5];

        const float* plane = x + ((size_t)(b * NN + n) * CC_DIM + cc * CPT) * HW;

        // ---- h0: geometry, load 2-row patch, consume ----
        int clA, rlA;
        float gA00, gA01, gA10, gA11;
        GEOM(gy0, clA, rlA, gA00, gA01, gA10, gA11)

        const int offA = rlA * WW + clA;
        float L0[CPT][2], L1[CPT][2];
#pragma unroll
        for (int c = 0; c < CPT; ++c) {
            const float* pc = plane + (size_t)c * HW + offA;
            __builtin_memcpy(&L0[c][0], pc, 8);
            __builtin_memcpy(&L1[c][0], pc + WW, 8);
        }

#pragma unroll
        for (int c = 0; c < CPT; ++c) {
            float v = L0[c][0] * gA00;
            v = fmaf(L0[c][1], gA01, v);
            v = fmaf(L1[c][0], gA10, v);
            v = fmaf(L1[c][1], gA11, v);
            acc0[c] = fmaxf(acc0[c], v);
        }

        // ---- h1: geometry AFTER h0 consume (limits liveness), then
        //      branch with in-place register reuse (no P/Q buffers) ----
        int clB, rlB;
        float gB00, gB01, gB10, gB11;
        GEOM(gy1, clB, rlB, gB00, gB01, gB10, gB11)

        const bool sameCol = (clB == clA);
        const bool reuse0 = sameCol && (rlB == rlA);      // patch identical: 0 loads
        const bool reuse1 = sameCol && (rlB == rlA + 1);  // shift by one row: 1 row load

        if (reuse0) {
#pragma unroll
            for (int c = 0; c < CPT; ++c) {
                float v = L0[c][0] * gB00;
                v = fmaf(L0[c][1], gB01, v);
                v = fmaf(L1[c][0], gB10, v);
                v = fmaf(L1[c][1], gB11, v);
                acc1[c] = fmaxf(acc1[c], v);
            }
        } else if (reuse1) {
            // rows: low = L1 (old high), high = fresh row rlB+1 loaded into L0 (dead)
            const int offQ = (rlB + 1) * WW + clB;
#pragma unroll
            for (int c = 0; c < CPT; ++c) {
                __builtin_memcpy(&L0[c][0], plane + (size_t)c * HW + offQ, 8);
            }
#pragma unroll
            for (int c = 0; c < CPT; ++c) {
                float v = L1[c][0] * gB00;
                v = fmaf(L1[c][1], gB01, v);
                v = fmaf(L0[c][0], gB10, v);
                v = fmaf(L0[c][1], gB11, v);
                acc1[c] = fmaxf(acc1[c], v);
            }
        } else {
            // full reload into L0/L1 (dead after h0 consume)
            const int offB = rlB * WW + clB;
#pragma unroll
            for (int c = 0; c < CPT; ++c) {
                const float* pc = plane + (size_t)c * HW + offB;
                __builtin_memcpy(&L0[c][0], pc, 8);
                __builtin_memcpy(&L1[c][0], pc + WW, 8);
            }
#pragma unroll
            for (int c = 0; c < CPT; ++c) {
                float v = L0[c][0] * gB00;
                v = fmaf(L0[c][1], gB01, v);
                v = fmaf(L1[c][0], gB10, v);
                v = fmaf(L1[c][1], gB11, v);
                acc1[c] = fmaxf(acc1[c], v);
            }
        }
    }
#undef GEOM

    // ---- write outputs: out[b, cc*CPT + c, h0/h1, w] ----
#pragma unroll
    for (int c = 0; c < CPT; ++c) {
        const size_t rowbase = ((size_t)(b * CC_DIM + cc * CPT + c) * HH + h0) * WW + w;
        out[rowbase] = acc0[c];
        out[rowbase + WW] = acc1[c];
    }

    if (idx == 0) {
        out[(size_t)BB * CC_DIM * HW] = 0.0f;  // communication_rates
    }
}

extern "C" void kernel_launch(void* const* d_in, const int* in_sizes, int n_in,
                              void* d_out, int out_size, void* d_ws, size_t ws_size,
                              hipStream_t stream) {
    const float* x = (const float*)d_in[0];
    const float* ptm = (const float*)d_in[3];
    float* out = (float*)d_out;

    const int total = BB * NCHUNK * HP * WW;  // 403200
    const int block = 256;
    const int grid = total / block;           // 1575
    where2comm_fuse_kernel<<<grid, block, 0, stream>>>(x, ptm, out);
}